// Round 5
// baseline (88.741 us; speedup 1.0000x reference)
//
#include <hip/hip_runtime.h>
#include <math.h>

#define B 64
#define P 1024
#define L 16
#define H 256
#define K 64

__device__ __forceinline__ float wsum(float v){
  #pragma unroll
  for (int o = 32; o >= 1; o >>= 1) v += __shfl_xor(v, o, 64);
  return v;
}
__device__ __forceinline__ float wmaxr(float v){
  #pragma unroll
  for (int o = 32; o >= 1; o >>= 1) v = fmaxf(v, __shfl_xor(v, o, 64));
  return v;
}
__device__ __forceinline__ void wargmax(float &v, int &i){
  #pragma unroll
  for (int o = 32; o >= 1; o >>= 1){
    float v2 = __shfl_xor(v, o, 64);
    int   i2 = __shfl_xor(i, o, 64);
    if (v2 > v || (v2 == v && i2 < i)){ v = v2; i = i2; }
  }
}
__device__ __forceinline__ unsigned fkey(float f){
  unsigned b = __float_as_uint(f);
  return (b & 0x80000000u) ? ~b : (b | 0x80000000u);
}
__device__ __forceinline__ float dot4(float4 a, float4 b){
  return a.x*b.x + a.y*b.y + a.z*b.z + a.w*b.w;
}

// ------ kernel 1: radix-select top-64 + IoU + w + precomputed iou-loss coeffs c ------
__global__ __launch_bounds__(256) void k_topk_iou(
    const float* __restrict__ pred_center, const float* __restrict__ pred_size,
    const float* __restrict__ obj, const float* __restrict__ ref_center,
    const int* __restrict__ ref_cls, const float* __restrict__ ref_res,
    const float* __restrict__ mean_sz, const int* __restrict__ epoch_p,
    const int* __restrict__ lang_num,
    int* __restrict__ inds, float* __restrict__ iou_ws, float* __restrict__ w_ws,
    float* __restrict__ c_ws)
{
  __shared__ int hist[256];
  __shared__ int s_digit, s_cum;
  __shared__ int waveTot[4];
  __shared__ int sel[K];
  __shared__ float ctrS[K][3], szS[K][3];
  int b = blockIdx.x, tid = threadIdx.x, lane = tid & 63, wave = tid >> 6;

  const float4* o4 = (const float4*)(obj + (size_t)b*P*2);
  float4 va = o4[tid*2], vb = o4[tid*2+1];
  unsigned kj[4] = { fkey(va.y - va.x), fkey(va.w - va.z),
                     fkey(vb.y - vb.x), fkey(vb.w - vb.z) };

  unsigned prefix = 0; int rem = K;
  for (int pass = 0; pass < 4; ++pass){
    int shift = 24 - pass*8;
    hist[tid] = 0;
    __syncthreads();
    #pragma unroll
    for (int j = 0; j < 4; ++j){
      unsigned kk = kj[j];
      bool cand = (pass == 0) || ((kk >> (shift + 8)) == prefix);
      if (cand) atomicAdd(&hist[(kk >> shift) & 0xff], 1);
    }
    __syncthreads();
    int d = 255 - tid;
    int h = hist[d];
    int s = h;
    #pragma unroll
    for (int o = 1; o < 64; o <<= 1){ int t = __shfl_up(s, o, 64); if (lane >= o) s += t; }
    if (lane == 63) waveTot[wave] = s;
    __syncthreads();
    #pragma unroll
    for (int q = 0; q < 3; ++q) if (q < wave) s += waveTot[q];
    if (s >= rem && s - h < rem){ s_digit = d; s_cum = s - h; }
    __syncthreads();
    prefix = (prefix << 8) | (unsigned)s_digit;
    rem -= s_cum;
    __syncthreads();
  }
  unsigned T = prefix;
  int remFinal = rem;

  int eqc = 0;
  #pragma unroll
  for (int j = 0; j < 4; ++j) eqc += (kj[j] == T) ? 1 : 0;
  int v = eqc;
  #pragma unroll
  for (int o = 1; o < 64; o <<= 1){ int t = __shfl_up(v, o, 64); if (lane >= o) v += t; }
  if (lane == 63) waveTot[wave] = v;
  __syncthreads();
  int off = 0;
  for (int q = 0; q < wave; ++q) off += waveTot[q];
  int e = off + v - eqc;
  __syncthreads();

  int selc = 0; bool ch[4];
  #pragma unroll
  for (int j = 0; j < 4; ++j){
    bool g = kj[j] > T;
    bool q = (kj[j] == T) && (e < remFinal);
    if (kj[j] == T) e++;
    ch[j] = g || q; selc += ch[j] ? 1 : 0;
  }
  v = selc;
  #pragma unroll
  for (int o = 1; o < 64; o <<= 1){ int t = __shfl_up(v, o, 64); if (lane >= o) v += t; }
  if (lane == 63) waveTot[wave] = v;
  __syncthreads();
  off = 0;
  for (int q = 0; q < wave; ++q) off += waveTot[q];
  int slot = off + v - selc;
  #pragma unroll
  for (int j = 0; j < 4; ++j) if (ch[j]) sel[slot++] = tid*4 + j;
  __syncthreads();

  if (tid < K){
    int idx = sel[tid];
    inds[b*K + tid] = idx;
    #pragma unroll
    for (int dd = 0; dd < 3; ++dd){
      ctrS[tid][dd] = pred_center[((size_t)b*P + idx)*3 + dd];
      szS [tid][dd] = pred_size [((size_t)b*P + idx)*3 + dd];
    }
  }
  __syncthreads();

  int ep = epoch_p[0];
  float pr = ep <= 0 ? 0.f : (ep >= 80 ? 1.f : ep / 80.f);
  float thr = 0.05f + 0.3f * pr;
  float gamma = 1.f + 2.f * pr;
  int ln = lang_num[b];

  for (int l = wave; l < L; l += 4){
    int cls = ref_cls[b*L + l];
    float gs[3], gc[3]; float volg = 1.f;
    #pragma unroll
    for (int dd = 0; dd < 3; ++dd){
      gs[dd] = mean_sz[cls*3+dd] + ref_res[((size_t)b*L+l)*3+dd] + 0.01f;
      gc[dd] = ref_center[((size_t)b*L+l)*3+dd];
      volg *= gs[dd];
    }
    int k = lane;
    float inter = 1.f, volp = 1.f;
    #pragma unroll
    for (int dd = 0; dd < 3; ++dd){
      float pc = ctrS[k][dd], ps = szS[k][dd];
      float lo = fmaxf(gc[dd]-gs[dd]*0.5f, pc-ps*0.5f);
      float hi = fminf(gc[dd]+gs[dd]*0.5f, pc+ps*0.5f);
      inter *= fmaxf(hi-lo, 0.f);
      volp *= ps;
    }
    float iou = inter / (volg + volp - inter + 1e-7f);
    float wv = (iou >= thr) ? powf(iou, gamma) : 0.f;
    float S = wsum(wv);
    float av = iou; int ai = k;
    wargmax(av, ai);
    float wfin = (S < 1e-6f) ? ((k == ai) ? 1.f : 0.f) : wv;
    iou_ws[((size_t)b*L + l)*K + k] = iou;
    w_ws  [((size_t)b*L + l)*K + k] = wfin;
    float Sf = (S < 1e-6f) ? 1.f : S;
    float a = wfin * Sf;
    float c = wfin / ((a + 1e-6f) * (a/(a + 1e-6f) + 1e-6f));
    c_ws[((size_t)b*L + l)*K + k] = (l < ln) ? c : 0.f;
  }
}

// ---------------- kernel 2: fused 3x GEMM, packed-transposed outputs ----------------
// Core identical to round-1 (22us known-good). Epilogue writes C^T packed:
// box mats: CT[b][hg=h>>2][r(64)][h&3]  (16384 floats per batch)
// tex mat : CT[b][hg=h>>2][l(16)][h&3]  ( 4096 floats per batch)
// so that k_contrast reads per-h-group coalesced float4s with zero LDS.
__global__ __launch_bounds__(256) void k_gemm(
    const float* __restrict__ bbox_feature, const int* __restrict__ inds,
    const float* __restrict__ lang_emb,
    const float* __restrict__ Wpc, const float* __restrict__ Wpci,
    const float* __restrict__ Wtext,
    float* __restrict__ cboxr, float* __restrict__ cboxri, float* __restrict__ ctexr)
{
  __shared__ float As[16][68], Ws[16][68];
  int gb = blockIdx.x;
  const float *W; float *C; int m0; bool gat;
  if (gb < 64)       { W = Wpc;   C = cboxr;  m0 = gb*64;       gat = true;  }
  else if (gb < 128) { W = Wpci;  C = cboxri; m0 = (gb-64)*64;  gat = true;  }
  else               { W = Wtext; C = ctexr;  m0 = (gb-128)*64; gat = false; }
  int bcol = blockIdx.y * 64;
  int tid = threadIdx.x;
  int lr = tid >> 2, lc = (tid & 3) * 4;
  int tr = tid >> 4, tc = tid & 15;
  int r = m0 + lr;
  const float* Arow = gat ? bbox_feature + ((size_t)(r >> 6)*P + inds[r])*H
                          : lang_emb + (size_t)r*H;
  const float* Wrow = W + (size_t)(bcol + lr)*H;
  float acc[4][4] = {};
  for (int h0 = 0; h0 < H; h0 += 16){
    float4 av = *(const float4*)&Arow[h0 + lc];
    float4 wv = *(const float4*)&Wrow[h0 + lc];
    As[lc+0][lr]=av.x; As[lc+1][lr]=av.y; As[lc+2][lr]=av.z; As[lc+3][lr]=av.w;
    Ws[lc+0][lr]=wv.x; Ws[lc+1][lr]=wv.y; Ws[lc+2][lr]=wv.z; Ws[lc+3][lr]=wv.w;
    __syncthreads();
    #pragma unroll
    for (int h = 0; h < 16; ++h){
      float4 a = *(const float4*)&As[h][tr*4];
      float4 w = *(const float4*)&Ws[h][tc*4];
      float aa[4] = {a.x,a.y,a.z,a.w};
      float ww[4] = {w.x,w.y,w.z,w.w};
      #pragma unroll
      for (int i = 0; i < 4; ++i)
        #pragma unroll
        for (int j = 0; j < 4; ++j) acc[i][j] += aa[i]*ww[j];
    }
    __syncthreads();
  }
  int hg = (bcol >> 2) + tc;               // h-group index 0..63
  #pragma unroll
  for (int i = 0; i < 4; ++i){
    float4 v = make_float4(acc[i][0],acc[i][1],acc[i][2],acc[i][3]);
    int rr = m0 + tr*4 + i;                // global output row
    if (gat){
      int bb = rr >> 6, rl = rr & 63;
      *(float4*)&C[(size_t)bb*16384 + hg*256 + rl*4] = v;
    } else {
      int bb = rr >> 4, rl = rr & 15;
      *(float4*)&C[(size_t)bb*4096  + hg*64  + rl*4] = v;
    }
  }
}

// ---------------- kernel 3: contrast losses, ZERO LDS, pure streaming ----------------
// blocks 0..63   : lang loss, batch b = blk
// blocks 64..319 : iou loss, idx=blk-64, b=idx>>2, rows r0=(idx&3)*16+wave*4
// Per h-group c: lane m reads its own float4 (coalesced 1KB/wave); the k/tex rows
// are wave-uniform loads. Norms accumulate in-register. No barriers at all.
__global__ __launch_bounds__(256) void k_contrast(
    const float* __restrict__ ctexr, const float* __restrict__ cboxr,
    const float* __restrict__ cboxri,
    const float* __restrict__ iou_ws, const float* __restrict__ w_ws,
    const float* __restrict__ c_ws,
    const int* __restrict__ lang_num, const float* __restrict__ log_inv_tau,
    const int* __restrict__ epoch_p, float* __restrict__ part)
{
  int tid = threadIdx.x, lane = tid & 63, wave = tid >> 6;
  int ep = epoch_p[0];
  float pr = ep <= 0 ? 0.f : (ep >= 80 ? 1.f : ep / 80.f);
  float min_tau = fmaxf(0.08f - 0.04f*pr, 1e-6f);
  float itau = fminf(fminf(expf(log_inv_tau[0]), 100.f), 1.f/min_tau);

  if (blockIdx.x < 64){
    // ---------------- lang branch ----------------
    int b = blockIdx.x;
    const float4* TB = (const float4*)cboxr + (size_t)b*4096;  // [64][64] f4
    const float4* TT = (const float4*)ctexr + (size_t)b*1024;  // [64][16] f4
    int l0 = wave*4;
    float acc[4] = {0,0,0,0}, nt2[4] = {0,0,0,0};
    float nb2 = 0.f;
    #pragma unroll 4
    for (int c = 0; c < 64; ++c){
      float4 bx = TB[c*64 + lane];
      nb2 += dot4(bx, bx);
      #pragma unroll
      for (int i = 0; i < 4; ++i){
        float4 tv = TT[c*16 + l0 + i];      // wave-uniform
        acc[i] += dot4(tv, bx);
        nt2[i] += dot4(tv, tv);
      }
    }
    float nb = fmaxf(sqrtf(nb2), 1e-12f);
    int ln = lang_num[b];
    float bacc = 0.f;
    #pragma unroll
    for (int i = 0; i < 4; ++i){
      int l = l0 + i;
      if (l < ln){
        float sv = acc[i] / (fmaxf(sqrtf(nt2[i]), 1e-12f) * nb);
        float wv  = w_ws [((size_t)b*L + l)*K + lane];
        float iou = iou_ws[((size_t)b*L + l)*K + lane];
        float S2 = wsum(wv);
        float target = wv / (S2 + 1e-6f);
        float tsum = S2 / (S2 + 1e-6f);
        float t2 = target / (tsum + 1e-6f);
        float z = sv * itau;
        float zmax = wmaxr(z);
        float se = wsum(expf(z - zmax));
        float lp = z - zmax - logf(se);
        float ce = -wsum(t2 * lp);
        bool neg = iou < 0.05f;
        float sneg = wmaxr(neg ? sv : -INFINITY);
        int anyneg = __any(neg);
        float spos = wsum(sv * target);
        float rank = anyneg ? fmaxf(0.2f - spos + sneg, 0.f) : 0.f;
        bacc += ce + 0.5f*rank;
      }
    }
    if (lane == 0) part[blockIdx.x*4 + wave] = bacc;
  } else {
    // ---------------- iou branch ----------------
    int idx = blockIdx.x - 64;
    int b = idx >> 2, r0 = (idx & 3)*16 + wave*4;
    const float4* TI = (const float4*)cboxri + (size_t)b*4096; // [64][64] f4
    float wl[16];
    #pragma unroll
    for (int l = 0; l < 16; ++l) wl[l] = w_ws[((size_t)b*L + l)*K + lane];
    float acc[4] = {0,0,0,0};
    float nm2 = 0.f;
    #pragma unroll 4
    for (int c = 0; c < 64; ++c){
      float4 bx = TI[c*64 + lane];
      nm2 += dot4(bx, bx);
      #pragma unroll
      for (int i = 0; i < 4; ++i){
        float4 kq = TI[c*64 + r0 + i];      // wave-uniform
        acc[i] += dot4(kq, bx);
      }
    }
    float nm = fmaxf(sqrtf(nm2), 1e-12f);
    float contrib = 0.f;
    #pragma unroll
    for (int i = 0; i < 4; ++i){
      float nk = __shfl(nm, r0 + i, 64);
      float sv = acc[i] / (nk * nm);
      float z = sv * itau;
      float zmax = wmaxr(z);
      float se = wsum(expf(z - zmax));
      float lp = z - zmax - logf(se);       // logp[row r0+i][col m=lane]
      float M = 0.f;
      #pragma unroll
      for (int l = 0; l < 16; ++l)
        M += c_ws[((size_t)b*L + l)*K + (r0 + i)] * wl[l];  // uniform c load
      contrib += M * lp;
    }
    float bacc = -wsum(contrib) * (1.f/64.f);
    if (lane == 0) part[256 + idx*4 + wave] = bacc;
  }
}

// ---------------- kernel 4: deterministic final reduce ----------------
__global__ __launch_bounds__(256) void k_final(const float* __restrict__ part,
                                               float* __restrict__ out)
{
  __shared__ float redI[4], redL[4];
  int tid = threadIdx.x, lane = tid & 63, wave = tid >> 6;
  float vl = part[tid];                                       // 256 lang partials
  float vi = part[256+tid] + part[512+tid] + part[768+tid] + part[1024+tid];
  vi = wsum(vi);
  vl = wsum(vl);
  if (lane == 0){ redI[wave] = vi; redL[wave] = vl; }
  __syncthreads();
  if (tid == 0){
    out[0] = (redL[0]+redL[1]+redL[2]+redL[3]) * (1.f/64.f);
    out[1] = (redI[0]+redI[1]+redI[2]+redI[3]) * (1.f/64.f);
  }
}

extern "C" void kernel_launch(void* const* d_in, const int* in_sizes, int n_in,
                              void* d_out, int out_size, void* d_ws, size_t ws_size,
                              hipStream_t stream)
{
  const float* pred_center = (const float*)d_in[0];
  const float* pred_size   = (const float*)d_in[1];
  const float* bbox_feature= (const float*)d_in[2];
  const float* obj         = (const float*)d_in[3];
  const float* lang_emb    = (const float*)d_in[4];
  const int*   lang_num    = (const int*)d_in[5];
  const float* ref_center  = (const float*)d_in[6];
  const int*   ref_cls     = (const int*)d_in[7];
  const float* ref_res     = (const float*)d_in[8];
  const float* mean_sz     = (const float*)d_in[9];
  const float* Wtext       = (const float*)d_in[10];
  const float* Wpc         = (const float*)d_in[11];
  const float* Wpci        = (const float*)d_in[12];
  const float* lit         = (const float*)d_in[13];
  const int*   epoch       = (const int*)d_in[14];

  float* ws = (float*)d_ws;
  int*   inds   = (int*)ws;                 // B*K ints
  float* iou_ws = ws + 4096;                // B*L*K
  float* w_ws   = iou_ws + B*L*K;           // B*L*K
  float* c_ws   = w_ws + B*L*K;             // B*L*K
  float* ctexr  = c_ws + B*L*K;             // B*L*H (packed-T)
  float* cboxr  = ctexr + (size_t)B*L*H;    // B*K*H (packed-T)
  float* cboxri = cboxr + (size_t)B*K*H;    // B*K*H (packed-T)
  float* part   = cboxri + (size_t)B*K*H;   // 256 lang + 1024 iou wave-partials

  k_topk_iou<<<B, 256, 0, stream>>>(pred_center, pred_size, obj, ref_center,
                                    ref_cls, ref_res, mean_sz, epoch, lang_num,
                                    inds, iou_ws, w_ws, c_ws);
  k_gemm<<<dim3(144, 4), 256, 0, stream>>>(bbox_feature, inds, lang_emb,
                                           Wpc, Wpci, Wtext, cboxr, cboxri, ctexr);
  k_contrast<<<320, 256, 0, stream>>>(ctexr, cboxr, cboxri,
                                      iou_ws, w_ws, c_ws, lang_num, lit,
                                      epoch, part);
  k_final<<<1, 256, 0, stream>>>(part, (float*)d_out);
}

// Round 6
// 75.399 us; speedup vs baseline: 1.1770x; 1.1770x over previous
//
#include <hip/hip_runtime.h>
#include <math.h>

#define B 64
#define P 1024
#define L 16
#define H 256
#define K 64

__device__ __forceinline__ float wsum(float v){
  #pragma unroll
  for (int o = 32; o >= 1; o >>= 1) v += __shfl_xor(v, o, 64);
  return v;
}
__device__ __forceinline__ float wmaxr(float v){
  #pragma unroll
  for (int o = 32; o >= 1; o >>= 1) v = fmaxf(v, __shfl_xor(v, o, 64));
  return v;
}
__device__ __forceinline__ void wargmax(float &v, int &i){
  #pragma unroll
  for (int o = 32; o >= 1; o >>= 1){
    float v2 = __shfl_xor(v, o, 64);
    int   i2 = __shfl_xor(i, o, 64);
    if (v2 > v || (v2 == v && i2 < i)){ v = v2; i = i2; }
  }
}
__device__ __forceinline__ unsigned fkey(float f){
  unsigned b = __float_as_uint(f);
  return (b & 0x80000000u) ? ~b : (b | 0x80000000u);
}
__device__ __forceinline__ float dot4(float4 a, float4 b){
  return a.x*b.x + a.y*b.y + a.z*b.z + a.w*b.w;
}

// ------ kernel 1: radix-select top-64 + IoU + w + precomputed iou-loss coeffs c ------
__global__ __launch_bounds__(256) void k_topk_iou(
    const float* __restrict__ pred_center, const float* __restrict__ pred_size,
    const float* __restrict__ obj, const float* __restrict__ ref_center,
    const int* __restrict__ ref_cls, const float* __restrict__ ref_res,
    const float* __restrict__ mean_sz, const int* __restrict__ epoch_p,
    const int* __restrict__ lang_num,
    int* __restrict__ inds, float* __restrict__ iou_ws, float* __restrict__ w_ws,
    float* __restrict__ c_ws)
{
  __shared__ int hist[256];
  __shared__ int s_digit, s_cum;
  __shared__ int waveTot[4];
  __shared__ int sel[K];
  __shared__ float ctrS[K][3], szS[K][3];
  int b = blockIdx.x, tid = threadIdx.x, lane = tid & 63, wave = tid >> 6;

  const float4* o4 = (const float4*)(obj + (size_t)b*P*2);
  float4 va = o4[tid*2], vb = o4[tid*2+1];
  unsigned kj[4] = { fkey(va.y - va.x), fkey(va.w - va.z),
                     fkey(vb.y - vb.x), fkey(vb.w - vb.z) };

  unsigned prefix = 0; int rem = K;
  for (int pass = 0; pass < 4; ++pass){
    int shift = 24 - pass*8;
    hist[tid] = 0;
    __syncthreads();
    #pragma unroll
    for (int j = 0; j < 4; ++j){
      unsigned kk = kj[j];
      bool cand = (pass == 0) || ((kk >> (shift + 8)) == prefix);
      if (cand) atomicAdd(&hist[(kk >> shift) & 0xff], 1);
    }
    __syncthreads();
    int d = 255 - tid;
    int h = hist[d];
    int s = h;
    #pragma unroll
    for (int o = 1; o < 64; o <<= 1){ int t = __shfl_up(s, o, 64); if (lane >= o) s += t; }
    if (lane == 63) waveTot[wave] = s;
    __syncthreads();
    #pragma unroll
    for (int q = 0; q < 3; ++q) if (q < wave) s += waveTot[q];
    if (s >= rem && s - h < rem){ s_digit = d; s_cum = s - h; }
    __syncthreads();
    prefix = (prefix << 8) | (unsigned)s_digit;
    rem -= s_cum;
    __syncthreads();
  }
  unsigned T = prefix;
  int remFinal = rem;

  int eqc = 0;
  #pragma unroll
  for (int j = 0; j < 4; ++j) eqc += (kj[j] == T) ? 1 : 0;
  int v = eqc;
  #pragma unroll
  for (int o = 1; o < 64; o <<= 1){ int t = __shfl_up(v, o, 64); if (lane >= o) v += t; }
  if (lane == 63) waveTot[wave] = v;
  __syncthreads();
  int off = 0;
  for (int q = 0; q < wave; ++q) off += waveTot[q];
  int e = off + v - eqc;
  __syncthreads();

  int selc = 0; bool ch[4];
  #pragma unroll
  for (int j = 0; j < 4; ++j){
    bool g = kj[j] > T;
    bool q = (kj[j] == T) && (e < remFinal);
    if (kj[j] == T) e++;
    ch[j] = g || q; selc += ch[j] ? 1 : 0;
  }
  v = selc;
  #pragma unroll
  for (int o = 1; o < 64; o <<= 1){ int t = __shfl_up(v, o, 64); if (lane >= o) v += t; }
  if (lane == 63) waveTot[wave] = v;
  __syncthreads();
  off = 0;
  for (int q = 0; q < wave; ++q) off += waveTot[q];
  int slot = off + v - selc;
  #pragma unroll
  for (int j = 0; j < 4; ++j) if (ch[j]) sel[slot++] = tid*4 + j;
  __syncthreads();

  if (tid < K){
    int idx = sel[tid];
    inds[b*K + tid] = idx;
    #pragma unroll
    for (int dd = 0; dd < 3; ++dd){
      ctrS[tid][dd] = pred_center[((size_t)b*P + idx)*3 + dd];
      szS [tid][dd] = pred_size [((size_t)b*P + idx)*3 + dd];
    }
  }
  __syncthreads();

  int ep = epoch_p[0];
  float pr = ep <= 0 ? 0.f : (ep >= 80 ? 1.f : ep / 80.f);
  float thr = 0.05f + 0.3f * pr;
  float gamma = 1.f + 2.f * pr;
  int ln = lang_num[b];

  for (int l = wave; l < L; l += 4){
    int cls = ref_cls[b*L + l];
    float gs[3], gc[3]; float volg = 1.f;
    #pragma unroll
    for (int dd = 0; dd < 3; ++dd){
      gs[dd] = mean_sz[cls*3+dd] + ref_res[((size_t)b*L+l)*3+dd] + 0.01f;
      gc[dd] = ref_center[((size_t)b*L+l)*3+dd];
      volg *= gs[dd];
    }
    int k = lane;
    float inter = 1.f, volp = 1.f;
    #pragma unroll
    for (int dd = 0; dd < 3; ++dd){
      float pc = ctrS[k][dd], ps = szS[k][dd];
      float lo = fmaxf(gc[dd]-gs[dd]*0.5f, pc-ps*0.5f);
      float hi = fminf(gc[dd]+gs[dd]*0.5f, pc+ps*0.5f);
      inter *= fmaxf(hi-lo, 0.f);
      volp *= ps;
    }
    float iou = inter / (volg + volp - inter + 1e-7f);
    float wv = (iou >= thr) ? powf(iou, gamma) : 0.f;
    float S = wsum(wv);
    float av = iou; int ai = k;
    wargmax(av, ai);
    float wfin = (S < 1e-6f) ? ((k == ai) ? 1.f : 0.f) : wv;
    iou_ws[((size_t)b*L + l)*K + k] = iou;
    w_ws  [((size_t)b*L + l)*K + k] = wfin;
    float Sf = (S < 1e-6f) ? 1.f : S;
    float a = wfin * Sf;
    float c = wfin / ((a + 1e-6f) * (a/(a + 1e-6f) + 1e-6f));
    c_ws[((size_t)b*L + l)*K + k] = (l < ln) ? c : 0.f;
  }
}

// ---------------- kernel 2: fused 3x GEMM ----------------
// Core identical to the known-good round-1 version.  Epilogue layouts:
//   cboxr  : packed-T  CT[b][hg=h>>2][r(64)][h&3]  (per-lane stream in lang)
//   cboxri : packed-T  (per-lane stream in iou)  +  boxri_rm row-major (broadcast stage)
//   texr_rm: row-major (broadcast stage in lang)
__global__ __launch_bounds__(256) void k_gemm(
    const float* __restrict__ bbox_feature, const int* __restrict__ inds,
    const float* __restrict__ lang_emb,
    const float* __restrict__ Wpc, const float* __restrict__ Wpci,
    const float* __restrict__ Wtext,
    float* __restrict__ cboxr, float* __restrict__ cboxri,
    float* __restrict__ boxri_rm, float* __restrict__ texr_rm)
{
  __shared__ float As[16][68], Ws[16][68];
  int gb = blockIdx.x;
  const float *W; int m0; bool gat;
  if (gb < 64)       { W = Wpc;   m0 = gb*64;       gat = true;  }
  else if (gb < 128) { W = Wpci;  m0 = (gb-64)*64;  gat = true;  }
  else               { W = Wtext; m0 = (gb-128)*64; gat = false; }
  int bcol = blockIdx.y * 64;
  int tid = threadIdx.x;
  int lr = tid >> 2, lc = (tid & 3) * 4;
  int tr = tid >> 4, tc = tid & 15;
  int r = m0 + lr;
  const float* Arow = gat ? bbox_feature + ((size_t)(r >> 6)*P + inds[r])*H
                          : lang_emb + (size_t)r*H;
  const float* Wrow = W + (size_t)(bcol + lr)*H;
  float acc[4][4] = {};
  for (int h0 = 0; h0 < H; h0 += 16){
    float4 av = *(const float4*)&Arow[h0 + lc];
    float4 wv = *(const float4*)&Wrow[h0 + lc];
    As[lc+0][lr]=av.x; As[lc+1][lr]=av.y; As[lc+2][lr]=av.z; As[lc+3][lr]=av.w;
    Ws[lc+0][lr]=wv.x; Ws[lc+1][lr]=wv.y; Ws[lc+2][lr]=wv.z; Ws[lc+3][lr]=wv.w;
    __syncthreads();
    #pragma unroll
    for (int h = 0; h < 16; ++h){
      float4 a = *(const float4*)&As[h][tr*4];
      float4 w = *(const float4*)&Ws[h][tc*4];
      float aa[4] = {a.x,a.y,a.z,a.w};
      float ww[4] = {w.x,w.y,w.z,w.w};
      #pragma unroll
      for (int i = 0; i < 4; ++i)
        #pragma unroll
        for (int j = 0; j < 4; ++j) acc[i][j] += aa[i]*ww[j];
    }
    __syncthreads();
  }
  int hg = (bcol >> 2) + tc;               // h-group index 0..63
  #pragma unroll
  for (int i = 0; i < 4; ++i){
    float4 v = make_float4(acc[i][0],acc[i][1],acc[i][2],acc[i][3]);
    int rr = m0 + tr*4 + i;                // global output row
    if (gb < 64){
      int bb = rr >> 6, rl = rr & 63;
      *(float4*)&cboxr[(size_t)bb*16384 + hg*256 + rl*4] = v;
    } else if (gb < 128){
      int bb = rr >> 6, rl = rr & 63;
      *(float4*)&cboxri[(size_t)bb*16384 + hg*256 + rl*4] = v;
      *(float4*)&boxri_rm[(size_t)rr*H + bcol + tc*4] = v;
    } else {
      *(float4*)&texr_rm[(size_t)rr*H + bcol + tc*4] = v;
    }
  }
}

// ---------------- kernel 3: contrast losses ----------------
// blocks 0..63   : lang loss, batch b.  Stage texr_rm[b] (16KB) in LDS; stream
//                  per-lane box rows from packed-T cboxr with 8-deep batching.
// blocks 64..319 : iou loss, idx=blk-64, b=idx>>2, strip=idx&3.  Stage 16
//                  broadcast rows of boxri_rm (16KB) + 1KB of c coeffs; stream
//                  per-lane rows from packed-T cboxri.
// Broadcast operands come from LDS (same-address b128 = free broadcast);
// per-lane stream has explicit 8-deep register batching for MLP.
__global__ __launch_bounds__(256) void k_contrast(
    const float* __restrict__ texr_rm, const float* __restrict__ cboxr,
    const float* __restrict__ cboxri, const float* __restrict__ boxri_rm,
    const float* __restrict__ iou_ws, const float* __restrict__ w_ws,
    const float* __restrict__ c_ws,
    const int* __restrict__ lang_num, const float* __restrict__ log_inv_tau,
    const int* __restrict__ epoch_p, float* __restrict__ part)
{
  __shared__ __align__(16) float4 SH[1024];   // 16KB broadcast rows [16][64] f4
  __shared__ float cL[256];                   // 1KB c coeffs (iou only)
  int tid = threadIdx.x, lane = tid & 63, wave = tid >> 6;
  int ep = epoch_p[0];
  float pr = ep <= 0 ? 0.f : (ep >= 80 ? 1.f : ep / 80.f);
  float min_tau = fmaxf(0.08f - 0.04f*pr, 1e-6f);
  float itau = fminf(fminf(expf(log_inv_tau[0]), 100.f), 1.f/min_tau);

  if (blockIdx.x < 64){
    // ---------------- lang branch ----------------
    int b = blockIdx.x;
    const float4* srcT = (const float4*)texr_rm + (size_t)b*1024;
    #pragma unroll
    for (int j = 0; j < 4; ++j) SH[tid + 256*j] = srcT[tid + 256*j];
    __syncthreads();

    const float4* TB = (const float4*)cboxr + (size_t)b*4096;
    int l0 = wave*4;
    float acc[4] = {0,0,0,0}, nt2[4] = {0,0,0,0};
    float nb2 = 0.f;
    for (int c0 = 0; c0 < 64; c0 += 8){
      float4 bx[8];
      #pragma unroll
      for (int u = 0; u < 8; ++u) bx[u] = TB[(c0+u)*64 + lane];
      #pragma unroll
      for (int u = 0; u < 8; ++u){
        nb2 += dot4(bx[u], bx[u]);
        #pragma unroll
        for (int i = 0; i < 4; ++i){
          float4 tv = SH[(l0+i)*64 + (c0+u)];   // LDS broadcast
          acc[i] += dot4(tv, bx[u]);
          nt2[i] += dot4(tv, tv);
        }
      }
    }
    float nb = fmaxf(sqrtf(nb2), 1e-12f);
    int ln = lang_num[b];
    float bacc = 0.f;
    #pragma unroll
    for (int i = 0; i < 4; ++i){
      int l = l0 + i;
      if (l < ln){
        float sv = acc[i] / (fmaxf(sqrtf(nt2[i]), 1e-12f) * nb);
        float wv  = w_ws [((size_t)b*L + l)*K + lane];
        float iou = iou_ws[((size_t)b*L + l)*K + lane];
        float S2 = wsum(wv);
        float target = wv / (S2 + 1e-6f);
        float tsum = S2 / (S2 + 1e-6f);
        float t2 = target / (tsum + 1e-6f);
        float z = sv * itau;
        float zmax = wmaxr(z);
        float se = wsum(expf(z - zmax));
        float lp = z - zmax - logf(se);
        float ce = -wsum(t2 * lp);
        bool neg = iou < 0.05f;
        float sneg = wmaxr(neg ? sv : -INFINITY);
        int anyneg = __any(neg);
        float spos = wsum(sv * target);
        float rank = anyneg ? fmaxf(0.2f - spos + sneg, 0.f) : 0.f;
        bacc += ce + 0.5f*rank;
      }
    }
    if (lane == 0) part[blockIdx.x*4 + wave] = bacc;
  } else {
    // ---------------- iou branch ----------------
    int idx = blockIdx.x - 64;
    int b = idx >> 2, strip = idx & 3;
    const float4* srcR = (const float4*)boxri_rm + (size_t)b*4096 + strip*1024;
    #pragma unroll
    for (int j = 0; j < 4; ++j) SH[tid + 256*j] = srcR[tid + 256*j];
    {
      int l = tid >> 4, kk = tid & 15;
      cL[l*16 + kk] = c_ws[((size_t)b*L + l)*K + strip*16 + kk];
    }
    float wl[16];
    #pragma unroll
    for (int l = 0; l < 16; ++l) wl[l] = w_ws[((size_t)b*L + l)*K + lane];
    __syncthreads();

    const float4* TI = (const float4*)cboxri + (size_t)b*4096;
    int r0 = strip*16 + wave*4;
    float acc[4] = {0,0,0,0};
    float nm2 = 0.f;
    for (int c0 = 0; c0 < 64; c0 += 8){
      float4 bx[8];
      #pragma unroll
      for (int u = 0; u < 8; ++u) bx[u] = TI[(c0+u)*64 + lane];
      #pragma unroll
      for (int u = 0; u < 8; ++u){
        nm2 += dot4(bx[u], bx[u]);
        #pragma unroll
        for (int i = 0; i < 4; ++i){
          float4 kq = SH[(wave*4+i)*64 + (c0+u)];   // LDS broadcast
          acc[i] += dot4(kq, bx[u]);
        }
      }
    }
    // per-wave c coefficients: one b128 per l (components = the wave's 4 k's)
    float4 Mv = make_float4(0.f,0.f,0.f,0.f);
    #pragma unroll
    for (int l = 0; l < 16; ++l){
      float4 cq = *(const float4*)&cL[l*16 + wave*4];
      Mv.x += cq.x * wl[l]; Mv.y += cq.y * wl[l];
      Mv.z += cq.z * wl[l]; Mv.w += cq.w * wl[l];
    }
    float Ma[4] = {Mv.x, Mv.y, Mv.z, Mv.w};
    float nm = fmaxf(sqrtf(nm2), 1e-12f);
    float contrib = 0.f;
    #pragma unroll
    for (int i = 0; i < 4; ++i){
      float nk = __shfl(nm, r0 + i, 64);
      float sv = acc[i] / (nk * nm);
      float z = sv * itau;
      float zmax = wmaxr(z);
      float se = wsum(expf(z - zmax));
      float lp = z - zmax - logf(se);       // logp[row r0+i][col m=lane]
      contrib += Ma[i] * lp;
    }
    float bacc = -wsum(contrib) * (1.f/64.f);
    if (lane == 0) part[256 + idx*4 + wave] = bacc;
  }
}

// ---------------- kernel 4: deterministic final reduce ----------------
__global__ __launch_bounds__(256) void k_final(const float* __restrict__ part,
                                               float* __restrict__ out)
{
  __shared__ float redI[4], redL[4];
  int tid = threadIdx.x, lane = tid & 63, wave = tid >> 6;
  float vl = part[tid];                                       // 256 lang partials
  float vi = part[256+tid] + part[512+tid] + part[768+tid] + part[1024+tid];
  vi = wsum(vi);
  vl = wsum(vl);
  if (lane == 0){ redI[wave] = vi; redL[wave] = vl; }
  __syncthreads();
  if (tid == 0){
    out[0] = (redL[0]+redL[1]+redL[2]+redL[3]) * (1.f/64.f);
    out[1] = (redI[0]+redI[1]+redI[2]+redI[3]) * (1.f/64.f);
  }
}

extern "C" void kernel_launch(void* const* d_in, const int* in_sizes, int n_in,
                              void* d_out, int out_size, void* d_ws, size_t ws_size,
                              hipStream_t stream)
{
  const float* pred_center = (const float*)d_in[0];
  const float* pred_size   = (const float*)d_in[1];
  const float* bbox_feature= (const float*)d_in[2];
  const float* obj         = (const float*)d_in[3];
  const float* lang_emb    = (const float*)d_in[4];
  const int*   lang_num    = (const int*)d_in[5];
  const float* ref_center  = (const float*)d_in[6];
  const int*   ref_cls     = (const int*)d_in[7];
  const float* ref_res     = (const float*)d_in[8];
  const float* mean_sz     = (const float*)d_in[9];
  const float* Wtext       = (const float*)d_in[10];
  const float* Wpc         = (const float*)d_in[11];
  const float* Wpci        = (const float*)d_in[12];
  const float* lit         = (const float*)d_in[13];
  const int*   epoch       = (const int*)d_in[14];

  float* ws = (float*)d_ws;
  int*   inds    = (int*)ws;                  // B*K ints
  float* iou_ws  = ws + 4096;                 // B*L*K
  float* w_ws    = iou_ws + B*L*K;            // B*L*K
  float* c_ws    = w_ws + B*L*K;              // B*L*K
  float* texr_rm = c_ws + B*L*K;              // B*L*H row-major
  float* cboxr   = texr_rm + (size_t)B*L*H;   // B*K*H packed-T
  float* cboxri  = cboxr + (size_t)B*K*H;     // B*K*H packed-T
  float* boxri_rm= cboxri + (size_t)B*K*H;    // B*K*H row-major
  float* part    = boxri_rm + (size_t)B*K*H;  // 256 lang + 1024 iou wave-partials

  k_topk_iou<<<B, 256, 0, stream>>>(pred_center, pred_size, obj, ref_center,
                                    ref_cls, ref_res, mean_sz, epoch, lang_num,
                                    inds, iou_ws, w_ws, c_ws);
  k_gemm<<<dim3(144, 4), 256, 0, stream>>>(bbox_feature, inds, lang_emb,
                                           Wpc, Wpci, Wtext,
                                           cboxr, cboxri, boxri_rm, texr_rm);
  k_contrast<<<320, 256, 0, stream>>>(texr_rm, cboxr, cboxri, boxri_rm,
                                      iou_ws, w_ws, c_ws, lang_num, lit,
                                      epoch, part);
  k_final<<<1, 256, 0, stream>>>(part, (float*)d_out);
}

// Round 7
// 62.081 us; speedup vs baseline: 1.4295x; 1.2145x over previous
//
#include <hip/hip_runtime.h>
#include <math.h>

#define B 64
#define P 1024
#define L 16
#define H 256
#define K 64

__device__ __forceinline__ float wsum(float v){
  #pragma unroll
  for (int o = 32; o >= 1; o >>= 1) v += __shfl_xor(v, o, 64);
  return v;
}
__device__ __forceinline__ float wmaxr(float v){
  #pragma unroll
  for (int o = 32; o >= 1; o >>= 1) v = fmaxf(v, __shfl_xor(v, o, 64));
  return v;
}
__device__ __forceinline__ void wargmax(float &v, int &i){
  #pragma unroll
  for (int o = 32; o >= 1; o >>= 1){
    float v2 = __shfl_xor(v, o, 64);
    int   i2 = __shfl_xor(i, o, 64);
    if (v2 > v || (v2 == v && i2 < i)){ v = v2; i = i2; }
  }
}
__device__ __forceinline__ unsigned fkey(float f){
  unsigned b = __float_as_uint(f);
  return (b & 0x80000000u) ? ~b : (b | 0x80000000u);
}
__device__ __forceinline__ float dot4(float4 a, float4 b){
  return a.x*b.x + a.y*b.y + a.z*b.z + a.w*b.w;
}
__device__ __forceinline__ int gsw(int r){ return (r ^ (r >> 3)) & 7; }

// ------ kernel 1: radix-select top-64 + IoU + w + precomputed loss coefficients ------
__global__ __launch_bounds__(256) void k_topk_iou(
    const float* __restrict__ pred_center, const float* __restrict__ pred_size,
    const float* __restrict__ obj, const float* __restrict__ ref_center,
    const int* __restrict__ ref_cls, const float* __restrict__ ref_res,
    const float* __restrict__ mean_sz, const int* __restrict__ epoch_p,
    const int* __restrict__ lang_num,
    int* __restrict__ inds, float* __restrict__ iou_ws, float* __restrict__ w_ws,
    float* __restrict__ c_ws, float* __restrict__ t_ws, float* __restrict__ t2_ws,
    float* __restrict__ t2s_ws)
{
  __shared__ int hist[256];
  __shared__ int s_digit, s_cum;
  __shared__ int waveTot[4];
  __shared__ int sel[K];
  __shared__ float ctrS[K][3], szS[K][3];
  int b = blockIdx.x, tid = threadIdx.x, lane = tid & 63, wave = tid >> 6;

  const float4* o4 = (const float4*)(obj + (size_t)b*P*2);
  float4 va = o4[tid*2], vb = o4[tid*2+1];
  unsigned kj[4] = { fkey(va.y - va.x), fkey(va.w - va.z),
                     fkey(vb.y - vb.x), fkey(vb.w - vb.z) };

  unsigned prefix = 0; int rem = K;
  for (int pass = 0; pass < 4; ++pass){
    int shift = 24 - pass*8;
    hist[tid] = 0;
    __syncthreads();
    #pragma unroll
    for (int j = 0; j < 4; ++j){
      unsigned kk = kj[j];
      bool cand = (pass == 0) || ((kk >> (shift + 8)) == prefix);
      if (cand) atomicAdd(&hist[(kk >> shift) & 0xff], 1);
    }
    __syncthreads();
    int d = 255 - tid;
    int h = hist[d];
    int s = h;
    #pragma unroll
    for (int o = 1; o < 64; o <<= 1){ int t = __shfl_up(s, o, 64); if (lane >= o) s += t; }
    if (lane == 63) waveTot[wave] = s;
    __syncthreads();
    #pragma unroll
    for (int q = 0; q < 3; ++q) if (q < wave) s += waveTot[q];
    if (s >= rem && s - h < rem){ s_digit = d; s_cum = s - h; }
    __syncthreads();
    prefix = (prefix << 8) | (unsigned)s_digit;
    rem -= s_cum;
    __syncthreads();
  }
  unsigned T = prefix;
  int remFinal = rem;

  int eqc = 0;
  #pragma unroll
  for (int j = 0; j < 4; ++j) eqc += (kj[j] == T) ? 1 : 0;
  int v = eqc;
  #pragma unroll
  for (int o = 1; o < 64; o <<= 1){ int t = __shfl_up(v, o, 64); if (lane >= o) v += t; }
  if (lane == 63) waveTot[wave] = v;
  __syncthreads();
  int off = 0;
  for (int q = 0; q < wave; ++q) off += waveTot[q];
  int e = off + v - eqc;
  __syncthreads();

  int selc = 0; bool ch[4];
  #pragma unroll
  for (int j = 0; j < 4; ++j){
    bool g = kj[j] > T;
    bool q = (kj[j] == T) && (e < remFinal);
    if (kj[j] == T) e++;
    ch[j] = g || q; selc += ch[j] ? 1 : 0;
  }
  v = selc;
  #pragma unroll
  for (int o = 1; o < 64; o <<= 1){ int t = __shfl_up(v, o, 64); if (lane >= o) v += t; }
  if (lane == 63) waveTot[wave] = v;
  __syncthreads();
  off = 0;
  for (int q = 0; q < wave; ++q) off += waveTot[q];
  int slot = off + v - selc;
  #pragma unroll
  for (int j = 0; j < 4; ++j) if (ch[j]) sel[slot++] = tid*4 + j;
  __syncthreads();

  if (tid < K){
    int idx = sel[tid];
    inds[b*K + tid] = idx;
    #pragma unroll
    for (int dd = 0; dd < 3; ++dd){
      ctrS[tid][dd] = pred_center[((size_t)b*P + idx)*3 + dd];
      szS [tid][dd] = pred_size [((size_t)b*P + idx)*3 + dd];
    }
  }
  __syncthreads();

  int ep = epoch_p[0];
  float pr = ep <= 0 ? 0.f : (ep >= 80 ? 1.f : ep / 80.f);
  float thr = 0.05f + 0.3f * pr;
  float gamma = 1.f + 2.f * pr;
  int ln = lang_num[b];

  for (int l = wave; l < L; l += 4){
    int cls = ref_cls[b*L + l];
    float gs[3], gc[3]; float volg = 1.f;
    #pragma unroll
    for (int dd = 0; dd < 3; ++dd){
      gs[dd] = mean_sz[cls*3+dd] + ref_res[((size_t)b*L+l)*3+dd] + 0.01f;
      gc[dd] = ref_center[((size_t)b*L+l)*3+dd];
      volg *= gs[dd];
    }
    int k = lane;
    float inter = 1.f, volp = 1.f;
    #pragma unroll
    for (int dd = 0; dd < 3; ++dd){
      float pc = ctrS[k][dd], ps = szS[k][dd];
      float lo = fmaxf(gc[dd]-gs[dd]*0.5f, pc-ps*0.5f);
      float hi = fminf(gc[dd]+gs[dd]*0.5f, pc+ps*0.5f);
      inter *= fmaxf(hi-lo, 0.f);
      volp *= ps;
    }
    float iou = inter / (volg + volp - inter + 1e-7f);
    float wv = (iou >= thr) ? powf(iou, gamma) : 0.f;
    float S = wsum(wv);
    float av = iou; int ai = k;
    wargmax(av, ai);
    float wfin = (S < 1e-6f) ? ((k == ai) ? 1.f : 0.f) : wv;
    iou_ws[((size_t)b*L + l)*K + k] = iou;
    w_ws  [((size_t)b*L + l)*K + k] = wfin;
    // iou-loss coefficient c (bilinear-M trick), l<ln mask folded in
    float Sf = (S < 1e-6f) ? 1.f : S;
    float a = wfin * Sf;
    float c = wfin / ((a + 1e-6f) * (a/(a + 1e-6f) + 1e-6f));
    c_ws[((size_t)b*L + l)*K + k] = (l < ln) ? c : 0.f;
    // lang-loss coefficients: target, t2, sum(t2)
    float target = wfin / (Sf + 1e-6f);
    float tsum = Sf / (Sf + 1e-6f);
    float t2 = target / (tsum + 1e-6f);
    t_ws [((size_t)b*L + l)*K + k] = target;
    t2_ws[((size_t)b*L + l)*K + k] = t2;
    float T2S = wsum(t2);
    if (lane == 0) t2s_ws[b*L + l] = T2S;
  }
}

// ---------------- kernel 2: fused 3x GEMM  C = A @ W^T (gather fused) ----------------
// Round-1 known-good version: [16][68] transposed tiles, immediate-offset b128 reads.
__global__ __launch_bounds__(256) void k_gemm(
    const float* __restrict__ bbox_feature, const int* __restrict__ inds,
    const float* __restrict__ lang_emb,
    const float* __restrict__ Wpc, const float* __restrict__ Wpci,
    const float* __restrict__ Wtext,
    float* __restrict__ boxr, float* __restrict__ boxri, float* __restrict__ texr)
{
  __shared__ float As[16][68], Ws[16][68];
  int gb = blockIdx.x;
  const float *W; float *C; int m0; bool gat;
  if (gb < 64)       { W = Wpc;   C = boxr;  m0 = gb*64;       gat = true;  }
  else if (gb < 128) { W = Wpci;  C = boxri; m0 = (gb-64)*64;  gat = true;  }
  else               { W = Wtext; C = texr;  m0 = (gb-128)*64; gat = false; }
  int bcol = blockIdx.y * 64;
  int tid = threadIdx.x;
  int lr = tid >> 2, lc = (tid & 3) * 4;
  int tr = tid >> 4, tc = tid & 15;
  int r = m0 + lr;
  const float* Arow = gat ? bbox_feature + ((size_t)(r >> 6)*P + inds[r])*H
                          : lang_emb + (size_t)r*H;
  const float* Wrow = W + (size_t)(bcol + lr)*H;
  float acc[4][4] = {};
  for (int h0 = 0; h0 < H; h0 += 16){
    float4 av = *(const float4*)&Arow[h0 + lc];
    float4 wv = *(const float4*)&Wrow[h0 + lc];
    As[lc+0][lr]=av.x; As[lc+1][lr]=av.y; As[lc+2][lr]=av.z; As[lc+3][lr]=av.w;
    Ws[lc+0][lr]=wv.x; Ws[lc+1][lr]=wv.y; Ws[lc+2][lr]=wv.z; Ws[lc+3][lr]=wv.w;
    __syncthreads();
    #pragma unroll
    for (int h = 0; h < 16; ++h){
      float4 a = *(const float4*)&As[h][tr*4];
      float4 w = *(const float4*)&Ws[h][tc*4];
      float aa[4] = {a.x,a.y,a.z,a.w};
      float ww[4] = {w.x,w.y,w.z,w.w};
      #pragma unroll
      for (int i = 0; i < 4; ++i)
        #pragma unroll
        for (int j = 0; j < 4; ++j) acc[i][j] += aa[i]*ww[j];
    }
    __syncthreads();
  }
  #pragma unroll
  for (int i = 0; i < 4; ++i){
    float4 v = make_float4(acc[i][0],acc[i][1],acc[i][2],acc[i][3]);
    *(float4*)&C[(size_t)(m0+tr*4+i)*H + bcol + tc*4] = v;
  }
}

// ---------------- kernel 3: contrast losses, 320 co-resident blocks ----------------
// r4-proven structure: blocks 0..63 lang (stage boxr 64KB + texr 16KB);
// blocks 64..319 iou (stage boxri 64KB + cL 1KB), 81920B dyn LDS -> 2 blocks/CU.
// Lang epilogue uses precomputed target/t2/sum(t2) (5 trees/row instead of 7);
// iou bilinear-M reads c coefficients from LDS (cL), not uniform global loads.
__global__ __launch_bounds__(256) void k_contrast(
    const float* __restrict__ texr, const float* __restrict__ boxr,
    const float* __restrict__ boxri,
    const float* __restrict__ iou_ws, const float* __restrict__ w_ws,
    const float* __restrict__ c_ws, const float* __restrict__ t_ws,
    const float* __restrict__ t2_ws, const float* __restrict__ t2s_ws,
    const int* __restrict__ lang_num, const float* __restrict__ log_inv_tau,
    const int* __restrict__ epoch_p, float* __restrict__ part)
{
  extern __shared__ __align__(16) float smem[];
  int tid = threadIdx.x, lane = tid & 63, wave = tid >> 6;
  int ep = epoch_p[0];
  float pr = ep <= 0 ? 0.f : (ep >= 80 ? 1.f : ep / 80.f);
  float min_tau = fmaxf(0.08f - 0.04f*pr, 1e-6f);
  float itau = fminf(fminf(expf(log_inv_tau[0]), 100.f), 1.f/min_tau);

  if (blockIdx.x < 64){
    // ---------------- lang branch ----------------
    int b = blockIdx.x;
    float4* TB = (float4*)smem;            // [64][64] boxr swizzled
    float4* TT = (float4*)smem + 4096;     // [16][64] texr swizzled
    const float4* srcB = (const float4*)(boxr + (size_t)b*K*H);
    const float4* srcT = (const float4*)(texr + (size_t)b*L*H);
    #pragma unroll
    for (int j = 0; j < 16; ++j){
      int i4 = tid + 256*j;
      int row = i4 >> 6, c = i4 & 63;
      TB[row*64 + (c ^ gsw(row))] = srcB[i4];
    }
    #pragma unroll
    for (int j = 0; j < 4; ++j){
      int i4 = tid + 256*j;
      int row = i4 >> 6, c = i4 & 63;
      TT[row*64 + (c ^ gsw(row))] = srcT[i4];
    }
    __syncthreads();

    float acc[4] = {0,0,0,0}, nt2[4] = {0,0,0,0};
    float nb2 = 0.f;
    for (int c = 0; c < 64; ++c){
      float4 bx = TB[lane*64 + (c ^ gsw(lane))];
      nb2 += dot4(bx, bx);
      #pragma unroll
      for (int i = 0; i < 4; ++i){
        int l = wave*4 + i;
        float4 tv = TT[l*64 + (c ^ gsw(l))];          // broadcast
        acc[i] += dot4(tv, bx);
        nt2[i] += dot4(tv, tv);
      }
    }
    float nb = fmaxf(sqrtf(nb2), 1e-12f);
    int ln = lang_num[b];
    float bacc = 0.f;
    #pragma unroll
    for (int i = 0; i < 4; ++i){
      int l = wave*4 + i;
      if (l < ln){
        float sv = acc[i] / (fmaxf(sqrtf(nt2[i]), 1e-12f) * nb);
        float target = t_ws [((size_t)b*L + l)*K + lane];
        float t2     = t2_ws[((size_t)b*L + l)*K + lane];
        float iou    = iou_ws[((size_t)b*L + l)*K + lane];
        float T2S    = t2s_ws[b*L + l];
        float z = sv * itau;
        float zmax = wmaxr(z);
        float se = wsum(expf(z - zmax));
        float t2z = wsum(t2 * z);
        float ce = -t2z + (zmax + logf(se)) * T2S;
        bool neg = iou < 0.05f;
        float sneg = wmaxr(neg ? sv : -INFINITY);
        int anyneg = __any(neg);
        float spos = wsum(sv * target);
        float rank = anyneg ? fmaxf(0.2f - spos + sneg, 0.f) : 0.f;
        bacc += ce + 0.5f*rank;
      }
    }
    if (lane == 0) part[blockIdx.x*4 + wave] = bacc;
  } else {
    // ---------------- iou branch ----------------
    int idx = blockIdx.x - 64;
    int b = idx >> 2, strip = idx & 3, r0 = strip*16 + wave*4;
    float4* TI = (float4*)smem;            // [64][64] boxri swizzled
    float*  cL = smem + 16384;             // [16][16] c coeffs for this strip
    const float4* srcI = (const float4*)(boxri + (size_t)b*K*H);
    #pragma unroll
    for (int j = 0; j < 16; ++j){
      int i4 = tid + 256*j;
      int row = i4 >> 6, c = i4 & 63;
      TI[row*64 + (c ^ gsw(row))] = srcI[i4];
    }
    {
      int l = tid >> 4, kk = tid & 15;
      cL[l*16 + kk] = c_ws[((size_t)b*L + l)*K + strip*16 + kk];
    }
    // prefetch w rows for all 16 l (per-lane column m = lane); c masks l >= ln
    float wl[16];
    #pragma unroll
    for (int l = 0; l < 16; ++l) wl[l] = w_ws[((size_t)b*L + l)*K + lane];
    __syncthreads();

    float acc[4] = {0,0,0,0};
    float nm2 = 0.f;
    for (int c = 0; c < 64; ++c){
      float4 bx = TI[lane*64 + (c ^ gsw(lane))];
      nm2 += dot4(bx, bx);
      #pragma unroll
      for (int i = 0; i < 4; ++i){
        float4 kq = TI[(r0+i)*64 + (c ^ gsw(r0+i))];  // broadcast
        acc[i] += dot4(kq, bx);
      }
    }
    // M[k] for the wave's 4 k-rows, vectorized: one b128 cL read per l
    float4 Mv = make_float4(0.f,0.f,0.f,0.f);
    #pragma unroll
    for (int l = 0; l < 16; ++l){
      float4 cq = *(const float4*)&cL[l*16 + wave*4];
      Mv.x += cq.x * wl[l]; Mv.y += cq.y * wl[l];
      Mv.z += cq.z * wl[l]; Mv.w += cq.w * wl[l];
    }
    float Ma[4] = {Mv.x, Mv.y, Mv.z, Mv.w};
    float nm = fmaxf(sqrtf(nm2), 1e-12f);
    float contrib = 0.f;
    #pragma unroll
    for (int i = 0; i < 4; ++i){
      float nk = __shfl(nm, r0 + i, 64);
      float sv = acc[i] / (nk * nm);
      float z = sv * itau;
      float zmax = wmaxr(z);
      float se = wsum(expf(z - zmax));
      float lp = z - zmax - logf(se);       // logp[row r0+i][col m=lane]
      contrib += Ma[i] * lp;
    }
    float bacc = -wsum(contrib) * (1.f/64.f);
    if (lane == 0) part[256 + idx*4 + wave] = bacc;
  }
}

// ---------------- kernel 4: deterministic final reduce ----------------
__global__ __launch_bounds__(256) void k_final(const float* __restrict__ part,
                                               float* __restrict__ out)
{
  __shared__ float redI[4], redL[4];
  int tid = threadIdx.x, lane = tid & 63, wave = tid >> 6;
  float vl = part[tid];                                       // 256 lang partials
  float vi = part[256+tid] + part[512+tid] + part[768+tid] + part[1024+tid];
  vi = wsum(vi);
  vl = wsum(vl);
  if (lane == 0){ redI[wave] = vi; redL[wave] = vl; }
  __syncthreads();
  if (tid == 0){
    out[0] = (redL[0]+redL[1]+redL[2]+redL[3]) * (1.f/64.f);
    out[1] = (redI[0]+redI[1]+redI[2]+redI[3]) * (1.f/64.f);
  }
}

extern "C" void kernel_launch(void* const* d_in, const int* in_sizes, int n_in,
                              void* d_out, int out_size, void* d_ws, size_t ws_size,
                              hipStream_t stream)
{
  const float* pred_center = (const float*)d_in[0];
  const float* pred_size   = (const float*)d_in[1];
  const float* bbox_feature= (const float*)d_in[2];
  const float* obj         = (const float*)d_in[3];
  const float* lang_emb    = (const float*)d_in[4];
  const int*   lang_num    = (const int*)d_in[5];
  const float* ref_center  = (const float*)d_in[6];
  const int*   ref_cls     = (const int*)d_in[7];
  const float* ref_res     = (const float*)d_in[8];
  const float* mean_sz     = (const float*)d_in[9];
  const float* Wtext       = (const float*)d_in[10];
  const float* Wpc         = (const float*)d_in[11];
  const float* Wpci        = (const float*)d_in[12];
  const float* lit         = (const float*)d_in[13];
  const int*   epoch       = (const int*)d_in[14];

  float* ws = (float*)d_ws;
  int*   inds   = (int*)ws;                 // B*K ints
  float* iou_ws = ws + 4096;                // B*L*K
  float* w_ws   = iou_ws + B*L*K;           // B*L*K
  float* c_ws   = w_ws + B*L*K;             // B*L*K
  float* t_ws   = c_ws + B*L*K;             // B*L*K
  float* t2_ws  = t_ws + B*L*K;             // B*L*K
  float* t2s_ws = t2_ws + B*L*K;            // B*L
  float* texr   = t2s_ws + B*L;             // B*L*H
  float* boxr   = texr + (size_t)B*L*H;     // B*K*H
  float* boxri  = boxr + (size_t)B*K*H;     // B*K*H
  float* part   = boxri + (size_t)B*K*H;    // 256 lang + 1024 iou wave-partials

  k_topk_iou<<<B, 256, 0, stream>>>(pred_center, pred_size, obj, ref_center,
                                    ref_cls, ref_res, mean_sz, epoch, lang_num,
                                    inds, iou_ws, w_ws, c_ws, t_ws, t2_ws, t2s_ws);
  k_gemm<<<dim3(144, 4), 256, 0, stream>>>(bbox_feature, inds, lang_emb,
                                           Wpc, Wpci, Wtext, boxr, boxri, texr);
  k_contrast<<<320, 256, 81920, stream>>>(texr, boxr, boxri,
                                          iou_ws, w_ws, c_ws, t_ws, t2_ws, t2s_ws,
                                          lang_num, lit, epoch, part);
  k_final<<<1, 256, 0, stream>>>(part, (float*)d_out);
}

// Round 8
// 56.724 us; speedup vs baseline: 1.5644x; 1.0944x over previous
//
#include <hip/hip_runtime.h>
#include <math.h>

#define B 64
#define P 1024
#define L 16
#define H 256
#define K 64

__device__ __forceinline__ float wsum(float v){
  #pragma unroll
  for (int o = 32; o >= 1; o >>= 1) v += __shfl_xor(v, o, 64);
  return v;
}
__device__ __forceinline__ float wmaxr(float v){
  #pragma unroll
  for (int o = 32; o >= 1; o >>= 1) v = fmaxf(v, __shfl_xor(v, o, 64));
  return v;
}
__device__ __forceinline__ void wargmax(float &v, int &i){
  #pragma unroll
  for (int o = 32; o >= 1; o >>= 1){
    float v2 = __shfl_xor(v, o, 64);
    int   i2 = __shfl_xor(i, o, 64);
    if (v2 > v || (v2 == v && i2 < i)){ v = v2; i = i2; }
  }
}
__device__ __forceinline__ unsigned fkey(float f){
  unsigned b = __float_as_uint(f);
  return (b & 0x80000000u) ? ~b : (b | 0x80000000u);
}
__device__ __forceinline__ float dot4(float4 a, float4 b){
  return a.x*b.x + a.y*b.y + a.z*b.z + a.w*b.w;
}
__device__ __forceinline__ int gsw(int r){ return (r ^ (r >> 3)) & 7; }

// ------ kernel 1: radix-select top-64 + IoU + w + precomputed loss coefficients ------
__global__ __launch_bounds__(256) void k_topk_iou(
    const float* __restrict__ pred_center, const float* __restrict__ pred_size,
    const float* __restrict__ obj, const float* __restrict__ ref_center,
    const int* __restrict__ ref_cls, const float* __restrict__ ref_res,
    const float* __restrict__ mean_sz, const int* __restrict__ epoch_p,
    const int* __restrict__ lang_num,
    int* __restrict__ inds, float* __restrict__ iou_ws, float* __restrict__ w_ws,
    float* __restrict__ c_ws, float* __restrict__ t_ws, float* __restrict__ t2_ws,
    float* __restrict__ t2s_ws)
{
  __shared__ int hist[256];
  __shared__ int s_digit, s_cum;
  __shared__ int waveTot[4];
  __shared__ int sel[K];
  __shared__ float ctrS[K][3], szS[K][3];
  int b = blockIdx.x, tid = threadIdx.x, lane = tid & 63, wave = tid >> 6;

  const float4* o4 = (const float4*)(obj + (size_t)b*P*2);
  float4 va = o4[tid*2], vb = o4[tid*2+1];
  unsigned kj[4] = { fkey(va.y - va.x), fkey(va.w - va.z),
                     fkey(vb.y - vb.x), fkey(vb.w - vb.z) };

  unsigned prefix = 0; int rem = K;
  for (int pass = 0; pass < 4; ++pass){
    int shift = 24 - pass*8;
    hist[tid] = 0;
    __syncthreads();
    #pragma unroll
    for (int j = 0; j < 4; ++j){
      unsigned kk = kj[j];
      bool cand = (pass == 0) || ((kk >> (shift + 8)) == prefix);
      if (cand) atomicAdd(&hist[(kk >> shift) & 0xff], 1);
    }
    __syncthreads();
    int d = 255 - tid;
    int h = hist[d];
    int s = h;
    #pragma unroll
    for (int o = 1; o < 64; o <<= 1){ int t = __shfl_up(s, o, 64); if (lane >= o) s += t; }
    if (lane == 63) waveTot[wave] = s;
    __syncthreads();
    #pragma unroll
    for (int q = 0; q < 3; ++q) if (q < wave) s += waveTot[q];
    if (s >= rem && s - h < rem){ s_digit = d; s_cum = s - h; }
    __syncthreads();
    prefix = (prefix << 8) | (unsigned)s_digit;
    rem -= s_cum;
    __syncthreads();
  }
  unsigned T = prefix;
  int remFinal = rem;

  int eqc = 0;
  #pragma unroll
  for (int j = 0; j < 4; ++j) eqc += (kj[j] == T) ? 1 : 0;
  int v = eqc;
  #pragma unroll
  for (int o = 1; o < 64; o <<= 1){ int t = __shfl_up(v, o, 64); if (lane >= o) v += t; }
  if (lane == 63) waveTot[wave] = v;
  __syncthreads();
  int off = 0;
  for (int q = 0; q < wave; ++q) off += waveTot[q];
  int e = off + v - eqc;
  __syncthreads();

  int selc = 0; bool ch[4];
  #pragma unroll
  for (int j = 0; j < 4; ++j){
    bool g = kj[j] > T;
    bool q = (kj[j] == T) && (e < remFinal);
    if (kj[j] == T) e++;
    ch[j] = g || q; selc += ch[j] ? 1 : 0;
  }
  v = selc;
  #pragma unroll
  for (int o = 1; o < 64; o <<= 1){ int t = __shfl_up(v, o, 64); if (lane >= o) v += t; }
  if (lane == 63) waveTot[wave] = v;
  __syncthreads();
  off = 0;
  for (int q = 0; q < wave; ++q) off += waveTot[q];
  int slot = off + v - selc;
  #pragma unroll
  for (int j = 0; j < 4; ++j) if (ch[j]) sel[slot++] = tid*4 + j;
  __syncthreads();

  if (tid < K){
    int idx = sel[tid];
    inds[b*K + tid] = idx;
    #pragma unroll
    for (int dd = 0; dd < 3; ++dd){
      ctrS[tid][dd] = pred_center[((size_t)b*P + idx)*3 + dd];
      szS [tid][dd] = pred_size [((size_t)b*P + idx)*3 + dd];
    }
  }
  __syncthreads();

  int ep = epoch_p[0];
  float pr = ep <= 0 ? 0.f : (ep >= 80 ? 1.f : ep / 80.f);
  float thr = 0.05f + 0.3f * pr;
  float gamma = 1.f + 2.f * pr;
  int ln = lang_num[b];

  for (int l = wave; l < L; l += 4){
    int cls = ref_cls[b*L + l];
    float gs[3], gc[3]; float volg = 1.f;
    #pragma unroll
    for (int dd = 0; dd < 3; ++dd){
      gs[dd] = mean_sz[cls*3+dd] + ref_res[((size_t)b*L+l)*3+dd] + 0.01f;
      gc[dd] = ref_center[((size_t)b*L+l)*3+dd];
      volg *= gs[dd];
    }
    int k = lane;
    float inter = 1.f, volp = 1.f;
    #pragma unroll
    for (int dd = 0; dd < 3; ++dd){
      float pc = ctrS[k][dd], ps = szS[k][dd];
      float lo = fmaxf(gc[dd]-gs[dd]*0.5f, pc-ps*0.5f);
      float hi = fminf(gc[dd]+gs[dd]*0.5f, pc+ps*0.5f);
      inter *= fmaxf(hi-lo, 0.f);
      volp *= ps;
    }
    float iou = inter / (volg + volp - inter + 1e-7f);
    float wv = (iou >= thr) ? powf(iou, gamma) : 0.f;
    float S = wsum(wv);
    float av = iou; int ai = k;
    wargmax(av, ai);
    float wfin = (S < 1e-6f) ? ((k == ai) ? 1.f : 0.f) : wv;
    iou_ws[((size_t)b*L + l)*K + k] = iou;
    w_ws  [((size_t)b*L + l)*K + k] = wfin;
    float Sf = (S < 1e-6f) ? 1.f : S;
    float a = wfin * Sf;
    float c = wfin / ((a + 1e-6f) * (a/(a + 1e-6f) + 1e-6f));
    c_ws[((size_t)b*L + l)*K + k] = (l < ln) ? c : 0.f;
    float target = wfin / (Sf + 1e-6f);
    float tsum = Sf / (Sf + 1e-6f);
    float t2 = target / (tsum + 1e-6f);
    t_ws [((size_t)b*L + l)*K + k] = target;
    t2_ws[((size_t)b*L + l)*K + k] = t2;
    float T2S = wsum(t2);
    if (lane == 0) t2s_ws[b*L + l] = T2S;
  }
}

// ---------------- kernel 2: fused 3x GEMM, 32-h chunks (half the barriers) ----------------
__global__ __launch_bounds__(256) void k_gemm(
    const float* __restrict__ bbox_feature, const int* __restrict__ inds,
    const float* __restrict__ lang_emb,
    const float* __restrict__ Wpc, const float* __restrict__ Wpci,
    const float* __restrict__ Wtext,
    float* __restrict__ boxr, float* __restrict__ boxri, float* __restrict__ texr)
{
  __shared__ float As[32][68], Ws[32][68];
  int gb = blockIdx.x;
  const float *W; float *C; int m0; bool gat;
  if (gb < 64)       { W = Wpc;   C = boxr;  m0 = gb*64;       gat = true;  }
  else if (gb < 128) { W = Wpci;  C = boxri; m0 = (gb-64)*64;  gat = true;  }
  else               { W = Wtext; C = texr;  m0 = (gb-128)*64; gat = false; }
  int bcol = blockIdx.y * 64;
  int tid = threadIdx.x;
  int lr = tid >> 2, lc = (tid & 3) * 4;
  int tr = tid >> 4, tc = tid & 15;
  int r = m0 + lr;
  const float* Arow = gat ? bbox_feature + ((size_t)(r >> 6)*P + inds[r])*H
                          : lang_emb + (size_t)r*H;
  const float* Wrow = W + (size_t)(bcol + lr)*H;
  float acc[4][4] = {};
  for (int h0 = 0; h0 < H; h0 += 32){
    float4 av  = *(const float4*)&Arow[h0 + lc];
    float4 av2 = *(const float4*)&Arow[h0 + 16 + lc];
    float4 wv  = *(const float4*)&Wrow[h0 + lc];
    float4 wv2 = *(const float4*)&Wrow[h0 + 16 + lc];
    As[lc+0][lr]=av.x;  As[lc+1][lr]=av.y;  As[lc+2][lr]=av.z;  As[lc+3][lr]=av.w;
    As[16+lc+0][lr]=av2.x; As[16+lc+1][lr]=av2.y; As[16+lc+2][lr]=av2.z; As[16+lc+3][lr]=av2.w;
    Ws[lc+0][lr]=wv.x;  Ws[lc+1][lr]=wv.y;  Ws[lc+2][lr]=wv.z;  Ws[lc+3][lr]=wv.w;
    Ws[16+lc+0][lr]=wv2.x; Ws[16+lc+1][lr]=wv2.y; Ws[16+lc+2][lr]=wv2.z; Ws[16+lc+3][lr]=wv2.w;
    __syncthreads();
    #pragma unroll
    for (int h = 0; h < 32; ++h){
      float4 a = *(const float4*)&As[h][tr*4];
      float4 w = *(const float4*)&Ws[h][tc*4];
      float aa[4] = {a.x,a.y,a.z,a.w};
      float ww[4] = {w.x,w.y,w.z,w.w};
      #pragma unroll
      for (int i = 0; i < 4; ++i)
        #pragma unroll
        for (int j = 0; j < 4; ++j) acc[i][j] += aa[i]*ww[j];
    }
    __syncthreads();
  }
  #pragma unroll
  for (int i = 0; i < 4; ++i){
    float4 v = make_float4(acc[i][0],acc[i][1],acc[i][2],acc[i][3]);
    *(float4*)&C[(size_t)(m0+tr*4+i)*H + bcol + tc*4] = v;
  }
}

// ---------------- kernel 3: contrast losses, 192 blocks x 512 threads ----------------
// blocks 0..63   : lang, batch b. 8 waves x 2 l-rows. Stage boxr 64KB + texr 16KB.
// blocks 64..191 : iou, idx=blk-64, b=idx>>1, half=idx&1 (rows half*32..+31),
//                  8 waves x 4 k-rows. Stage boxri 64KB once + cL 2KB.
// All 192 blocks co-resident (<=1 block/CU): critical path = ONE block.
__global__ __launch_bounds__(512) void k_contrast(
    const float* __restrict__ texr, const float* __restrict__ boxr,
    const float* __restrict__ boxri,
    const float* __restrict__ iou_ws, const float* __restrict__ w_ws,
    const float* __restrict__ c_ws, const float* __restrict__ t_ws,
    const float* __restrict__ t2_ws, const float* __restrict__ t2s_ws,
    const int* __restrict__ lang_num, const float* __restrict__ log_inv_tau,
    const int* __restrict__ epoch_p, float* __restrict__ part)
{
  extern __shared__ __align__(16) float smem[];
  int tid = threadIdx.x, lane = tid & 63, wave = tid >> 6;   // wave 0..7
  int ep = epoch_p[0];
  float pr = ep <= 0 ? 0.f : (ep >= 80 ? 1.f : ep / 80.f);
  float min_tau = fmaxf(0.08f - 0.04f*pr, 1e-6f);
  float itau = fminf(fminf(expf(log_inv_tau[0]), 100.f), 1.f/min_tau);

  if (blockIdx.x < 64){
    // ---------------- lang branch: 8 waves x 2 rows ----------------
    int b = blockIdx.x;
    float4* TB = (float4*)smem;            // [64][64] boxr swizzled
    float4* TT = (float4*)smem + 4096;     // [16][64] texr swizzled
    const float4* srcB = (const float4*)(boxr + (size_t)b*K*H);
    const float4* srcT = (const float4*)(texr + (size_t)b*L*H);
    #pragma unroll
    for (int j = 0; j < 8; ++j){
      int i4 = tid + 512*j;                // 0..4095
      int row = i4 >> 6, c = i4 & 63;
      TB[row*64 + (c ^ gsw(row))] = srcB[i4];
    }
    #pragma unroll
    for (int j = 0; j < 2; ++j){
      int i4 = tid + 512*j;                // 0..1023
      int row = i4 >> 6, c = i4 & 63;
      TT[row*64 + (c ^ gsw(row))] = srcT[i4];
    }
    __syncthreads();

    int l0 = wave*2;
    float acc[2] = {0,0}, nt2[2] = {0,0};
    float nb2 = 0.f;
    for (int c = 0; c < 64; ++c){
      float4 bx = TB[lane*64 + (c ^ gsw(lane))];
      nb2 += dot4(bx, bx);
      #pragma unroll
      for (int i = 0; i < 2; ++i){
        int l = l0 + i;
        float4 tv = TT[l*64 + (c ^ gsw(l))];          // broadcast
        acc[i] += dot4(tv, bx);
        nt2[i] += dot4(tv, tv);
      }
    }
    float nb = fmaxf(sqrtf(nb2), 1e-12f);
    int ln = lang_num[b];
    float bacc = 0.f;
    #pragma unroll
    for (int i = 0; i < 2; ++i){
      int l = l0 + i;
      if (l < ln){
        float sv = acc[i] / (fmaxf(sqrtf(nt2[i]), 1e-12f) * nb);
        float target = t_ws [((size_t)b*L + l)*K + lane];
        float t2     = t2_ws[((size_t)b*L + l)*K + lane];
        float iou    = iou_ws[((size_t)b*L + l)*K + lane];
        float T2S    = t2s_ws[b*L + l];
        float z = sv * itau;
        float zmax = wmaxr(z);
        float se = wsum(expf(z - zmax));
        float t2z = wsum(t2 * z);
        float ce = -t2z + (zmax + logf(se)) * T2S;
        bool neg = iou < 0.05f;
        float sneg = wmaxr(neg ? sv : -INFINITY);
        int anyneg = __any(neg);
        float spos = wsum(sv * target);
        float rank = anyneg ? fmaxf(0.2f - spos + sneg, 0.f) : 0.f;
        bacc += ce + 0.5f*rank;
      }
    }
    if (lane == 0) part[blockIdx.x*8 + wave] = bacc;
  } else {
    // ---------------- iou branch: 8 waves x 4 rows, single staging ----------------
    int idx = blockIdx.x - 64;
    int b = idx >> 1, half = idx & 1;
    int r0 = half*32 + wave*4;
    float4* TI = (float4*)smem;            // [64][64] boxri swizzled
    float*  cL = smem + 16384;             // [16][32] c coeffs for this half
    const float4* srcI = (const float4*)(boxri + (size_t)b*K*H);
    #pragma unroll
    for (int j = 0; j < 8; ++j){
      int i4 = tid + 512*j;                // 0..4095
      int row = i4 >> 6, c = i4 & 63;
      TI[row*64 + (c ^ gsw(row))] = srcI[i4];
    }
    {
      int l = tid >> 5, kk = tid & 31;     // 512 threads -> all 16x32 entries
      cL[l*32 + kk] = c_ws[((size_t)b*L + l)*K + half*32 + kk];
    }
    float wl[16];
    #pragma unroll
    for (int l = 0; l < 16; ++l) wl[l] = w_ws[((size_t)b*L + l)*K + lane];
    __syncthreads();

    float acc[4] = {0,0,0,0};
    float nm2 = 0.f;
    for (int c = 0; c < 64; ++c){
      float4 bx = TI[lane*64 + (c ^ gsw(lane))];
      nm2 += dot4(bx, bx);
      #pragma unroll
      for (int i = 0; i < 4; ++i){
        float4 kq = TI[(r0+i)*64 + (c ^ gsw(r0+i))];  // broadcast
        acc[i] += dot4(kq, bx);
      }
    }
    // M[k] for the wave's 4 k-rows: one b128 cL read per l
    float4 Mv = make_float4(0.f,0.f,0.f,0.f);
    #pragma unroll
    for (int l = 0; l < 16; ++l){
      float4 cq = *(const float4*)&cL[l*32 + wave*4];
      Mv.x += cq.x * wl[l]; Mv.y += cq.y * wl[l];
      Mv.z += cq.z * wl[l]; Mv.w += cq.w * wl[l];
    }
    float Ma[4] = {Mv.x, Mv.y, Mv.z, Mv.w};
    float nm = fmaxf(sqrtf(nm2), 1e-12f);
    float contrib = 0.f;
    #pragma unroll
    for (int i = 0; i < 4; ++i){
      float nk = __shfl(nm, r0 + i, 64);
      float sv = acc[i] / (nk * nm);
      float z = sv * itau;
      float zmax = wmaxr(z);
      float se = wsum(expf(z - zmax));
      float lp = z - zmax - logf(se);       // logp[row r0+i][col m=lane]
      contrib += Ma[i] * lp;
    }
    float bacc = -wsum(contrib) * (1.f/64.f);
    if (lane == 0) part[512 + idx*8 + wave] = bacc;
  }
}

// ---------------- kernel 4: deterministic final reduce ----------------
__global__ __launch_bounds__(256) void k_final(const float* __restrict__ part,
                                               float* __restrict__ out)
{
  __shared__ float redI[4], redL[4];
  int tid = threadIdx.x, lane = tid & 63, wave = tid >> 6;
  float vl = part[tid] + part[256+tid];                       // 512 lang partials
  float vi = part[512+tid] + part[768+tid] + part[1024+tid] + part[1280+tid];
  vi = wsum(vi);
  vl = wsum(vl);
  if (lane == 0){ redI[wave] = vi; redL[wave] = vl; }
  __syncthreads();
  if (tid == 0){
    out[0] = (redL[0]+redL[1]+redL[2]+redL[3]) * (1.f/64.f);
    out[1] = (redI[0]+redI[1]+redI[2]+redI[3]) * (1.f/64.f);
  }
}

extern "C" void kernel_launch(void* const* d_in, const int* in_sizes, int n_in,
                              void* d_out, int out_size, void* d_ws, size_t ws_size,
                              hipStream_t stream)
{
  const float* pred_center = (const float*)d_in[0];
  const float* pred_size   = (const float*)d_in[1];
  const float* bbox_feature= (const float*)d_in[2];
  const float* obj         = (const float*)d_in[3];
  const float* lang_emb    = (const float*)d_in[4];
  const int*   lang_num    = (const int*)d_in[5];
  const float* ref_center  = (const float*)d_in[6];
  const int*   ref_cls     = (const int*)d_in[7];
  const float* ref_res     = (const float*)d_in[8];
  const float* mean_sz     = (const float*)d_in[9];
  const float* Wtext       = (const float*)d_in[10];
  const float* Wpc         = (const float*)d_in[11];
  const float* Wpci        = (const float*)d_in[12];
  const float* lit         = (const float*)d_in[13];
  const int*   epoch       = (const int*)d_in[14];

  float* ws = (float*)d_ws;
  int*   inds   = (int*)ws;                 // B*K ints
  float* iou_ws = ws + 4096;                // B*L*K
  float* w_ws   = iou_ws + B*L*K;           // B*L*K
  float* c_ws   = w_ws + B*L*K;             // B*L*K
  float* t_ws   = c_ws + B*L*K;             // B*L*K
  float* t2_ws  = t_ws + B*L*K;             // B*L*K
  float* t2s_ws = t2_ws + B*L*K;            // B*L
  float* texr   = t2s_ws + B*L;             // B*L*H
  float* boxr   = texr + (size_t)B*L*H;     // B*K*H
  float* boxri  = boxr + (size_t)B*K*H;     // B*K*H
  float* part   = boxri + (size_t)B*K*H;    // 512 lang + 1024 iou wave-partials

  k_topk_iou<<<B, 256, 0, stream>>>(pred_center, pred_size, obj, ref_center,
                                    ref_cls, ref_res, mean_sz, epoch, lang_num,
                                    inds, iou_ws, w_ws, c_ws, t_ws, t2_ws, t2s_ws);
  k_gemm<<<dim3(144, 4), 256, 0, stream>>>(bbox_feature, inds, lang_emb,
                                           Wpc, Wpci, Wtext, boxr, boxri, texr);
  k_contrast<<<192, 512, 81920, stream>>>(texr, boxr, boxri,
                                          iou_ws, w_ws, c_ws, t_ws, t2_ws, t2s_ws,
                                          lang_num, lit, epoch, part);
  k_final<<<1, 256, 0, stream>>>(part, (float*)d_out);
}